// Round 12
// baseline (132.893 us; speedup 1.0000x reference)
//
#include <hip/hip_runtime.h>
#include <hip/hip_bf16.h>

// Fused 34->128->128->1 MLP, bf16 MFMA, transposed GEMMs.
// R12: 2x2 WAVE SPLIT. Wave (h2,p2) owns hidden [h2*64,+64) x points
// [p2*32,+32). Evidence (R5 occ-neutral, R11 barrier-neutral, R6/R7/R10
// LDS-cuts all won): kernel is LDS-pipe issue-bound; the 4-way hidden
// split made every wave read 3/4 of H0 (48 b128) + all of A0 (32).
// Now: L0 reads 16 (own points only), L1 reads 16 (own L0 output covers
// half the K-range, register-forwarded), epi0 16 b128, staging 8,
// PART 8+8 b32  => ~72 DS instrs/tile (was ~136).
// Storage-order assignment: MFMA position (h2,hb,q,r) computes TRUE
// hidden h = h2*64 + (hb>>1)*32 + q*8 + (hb&1)*4 + r, so the lane's
// L0 C/D values are contiguous 8-bf16 runs = exactly the L1 B-frags
// for its own two 32-k chunks (uint4 own[pb][ktl]).
// W1 loaded ROTATED (w1r[hb][kk], ktg=(h2*2+kk)&3) so own[] is consumed
// at literal kk=0,1 and dies (R9/R10 spill lesson).
// Cost: W1 frags 64 VGPRs (total ~220) -> (256,2), grid 512 = 2 blk/CU.
// Tripwire: WRITE_SIZE >> 4MB = spill (R3/R8/R9).

using bf16x8 = __attribute__((ext_vector_type(8))) short;   // 8 bf16 = 4 VGPRs
using f32x4  = __attribute__((ext_vector_type(4))) float;   // MFMA C/D

#define NPTS    1000000
#define NUMEMB  6572
#define HID     128
#define M_IT    64          // points per block-iteration
#define A0S     72          // A0 row stride in bf16 (144B, 16B-aligned rows)
#define H0S     136         // H0 row stride in bf16 (272B, 16B-aligned rows)
#define TILES   (NPTS / M_IT)   // 15625 exactly
#define NBLOCKS 512         // 2 blocks/CU on 256 CUs

__device__ __forceinline__ unsigned short bf16r(float f) {
    unsigned u;
    __builtin_memcpy(&u, &f, 4);
    u = (u + 0x7fffu + ((u >> 16) & 1u)) >> 16;
    return (unsigned short)u;
}
__device__ __forceinline__ unsigned pk2(float a, float b) {
    // packed RNE f32x2 -> bf16x2 (v_cvt_pk_bf16_f32 on gfx950)
    float2 f2; f2.x = a; f2.y = b;
    __hip_bfloat162 h = __float22bfloat162_rn(f2);
    unsigned u;
    __builtin_memcpy(&u, &h, 4);
    return u;
}
__device__ __forceinline__ float clamp01(float x) {
    return __builtin_amdgcn_fmed3f(x, 0.f, 1.f);
}

__global__ __launch_bounds__(256, 2)
void mlp_fused(const float* __restrict__ x,
               const float* __restrict__ emb,
               const float* __restrict__ em_table,
               const float* __restrict__ W0, const float* __restrict__ b0,
               const float* __restrict__ W1, const float* __restrict__ b1,
               const float* __restrict__ W2, const float* __restrict__ b2,
               float* __restrict__ out)
{
    __shared__ __align__(16) unsigned short A0[2 * M_IT * A0S]; // dbuf [pt][in]
    __shared__ __align__(16) unsigned short H0[M_IT * H0S];     // [pt][h1]
    __shared__ __align__(16) float PART2[8][65];                // [h2*4+q][pt]

    const int tid  = threadIdx.x;
    const int lane = tid & 63;
    const int w    = tid >> 6;
    const int h2   = w & 1;      // hidden half  [h2*64, +64)
    const int p2   = w >> 1;     // point half   [p2*32, +32)
    const int q    = lane >> 4;  // quad within wave
    const int cl   = lane & 15;
    const int p    = tid >> 2;   // staging: point within tile
    const int s    = tid & 3;    // staging: 8-dim segment of embedding
    const int pbase = p2 * 32;

    // zero both A0 buffers once (cols 34..71 stay zero forever)
    for (int i = tid; i < 2 * M_IT * A0S; i += 256) A0[i] = 0;

    // ---- one-time: weight A-fragments into registers ----
    // A-frag lane (q,cl) holds A[m=cl][k=q*8+e]. MFMA position (hb, m)
    // computes TRUE hidden h = h2*64 + (hb>>1)*32 + (m>>2)*8 + (hb&1)*4
    // + (m&3)  (m -> C/D position (q=m>>2, r=m&3)).
    const int mrow = (cl >> 2) * 8 + (cl & 3);
    // W0 logical row k: k<32 -> em row 2+k ; k==32 -> x row 0 ; k==33 -> 1.
    bf16x8 w0t[4][2];   // [hb][kt]
    for (int hb = 0; hb < 4; ++hb)
        for (int kt = 0; kt < 2; ++kt) {
            const int col = h2 * 64 + (hb >> 1) * 32 + mrow + (hb & 1) * 4;
            bf16x8 v;
            #pragma unroll
            for (int e = 0; e < 8; ++e) {
                const int k = kt * 32 + q * 8 + e;
                float val = 0.f;
                if (k < 32)       val = W0[(2 + k) * HID + col];
                else if (k == 32) val = W0[0 * HID + col];
                else if (k == 33) val = W0[1 * HID + col];
                v[e] = (short)bf16r(val);
            }
            w0t[hb][kt] = v;
        }

    // W1 ROTATED: w1r[hb][kk] holds k-chunk ktg=(h2*2+kk)&3; kk=0,1 are
    // the wave's OWN chunks (consume own[] frags, which then die).
    bf16x8 w1r[4][4];   // [hb][kk]
    for (int hb = 0; hb < 4; ++hb)
        for (int kk = 0; kk < 4; ++kk) {
            const int ktg = (h2 * 2 + kk) & 3;
            const int col = h2 * 64 + (hb >> 1) * 32 + mrow + (hb & 1) * 4;
            bf16x8 v;
            #pragma unroll
            for (int e = 0; e < 8; ++e) {
                const int k = ktg * 32 + q * 8 + e;
                v[e] = (short)bf16r(W1[k * HID + col]);
            }
            w1r[hb][kk] = v;
        }

    // biases / W2 at this lane's true h = h2*64+(hb>>1)*32+q*8+(hb&1)*4+r
    f32x4 b0q[4], b1q[4], w2q[4];
    for (int hb = 0; hb < 4; ++hb)
        for (int r = 0; r < 4; ++r) {
            const int h = h2 * 64 + (hb >> 1) * 32 + q * 8 + (hb & 1) * 4 + r;
            b0q[hb][r] = b0[h];
            b1q[hb][r] = b1[h];
            w2q[hb][r] = W2[h];
        }
    const float bias2 = b2[0];

    // ---- prologue: stage tile t0 into buf 0; prefetch fe/x for t0+grid ----
    int t = blockIdx.x;
    int cur = 0;
    {
        const int gp = t * M_IT + p;
        const float fe = emb[gp];
        float2 xv = {0.f, 0.f};
        if (s == 0) xv = *(const float2*)(x + 2 * gp);
        const int e1 = (int)fe;
        const int e2 = (e1 + 1 < NUMEMB) ? e1 + 1 : NUMEMB - 1;
        const float r = fe - (float)e1;
        const float4* p1 = (const float4*)(em_table + e1 * 32 + s * 8);
        const float4* p2p = (const float4*)(em_table + e2 * 32 + s * 8);
        const float4 g0 = p1[0], g1 = p1[1], g2 = p2p[0], g3 = p2p[1];
        uint4 d;
        d.x = pk2(g0.x + (g2.x - g0.x) * r, g0.y + (g2.y - g0.y) * r);
        d.y = pk2(g0.z + (g2.z - g0.z) * r, g0.w + (g2.w - g0.w) * r);
        d.z = pk2(g1.x + (g3.x - g1.x) * r, g1.y + (g3.y - g1.y) * r);
        d.w = pk2(g1.z + (g3.z - g1.z) * r, g1.w + (g3.w - g1.w) * r);
        *(uint4*)&A0[p * A0S + s * 8] = d;
        if (s == 0) *(unsigned*)&A0[p * A0S + 32] = pk2(xv.x, xv.y);
    }
    float  feB;
    float2 xvB = {0.f, 0.f};
    {
        int t1 = t + gridDim.x; if (t1 >= TILES) t1 = t;
        const int gp = t1 * M_IT + p;
        feB = emb[gp];
        if (s == 0) xvB = *(const float2*)(x + 2 * gp);
    }

    __syncthreads();   // A0 zero + first staging visible

    for (; t < TILES; t += gridDim.x, cur ^= 1) {
        const int base = t * M_IT;
        const unsigned short* A0c = A0 + cur * (M_IT * A0S);
        unsigned short*       A0n = A0 + (cur ^ 1) * (M_IT * A0S);

        // ---- layer 0: D[h own 64][p own 32], bias in acc ----
        f32x4 acc[2][4];   // [pb][hb]
        #pragma unroll
        for (int pb = 0; pb < 2; ++pb)
            #pragma unroll
            for (int hb = 0; hb < 4; ++hb)
                acc[pb][hb] = b0q[hb];
        #pragma unroll
        for (int pb = 0; pb < 2; ++pb) {
            #pragma unroll
            for (int kt = 0; kt < 2; ++kt) {
                bf16x8 bfrag = *(const bf16x8*)
                    &A0c[(pbase + pb * 16 + cl) * A0S + kt * 32 + q * 8];
                #pragma unroll
                for (int hb = 0; hb < 4; ++hb)
                    acc[pb][hb] = __builtin_amdgcn_mfma_f32_16x16x32_bf16(
                        w0t[hb][kt], bfrag, acc[pb][hb], 0, 0, 0);
            }
        }

        // ---- issue gathers for tile t+1 (feB ready; short liveness) ----
        const int ge1 = (int)feB;
        const int ge2 = (ge1 + 1 < NUMEMB) ? ge1 + 1 : NUMEMB - 1;
        const float4* gp1 = (const float4*)(em_table + ge1 * 32 + s * 8);
        const float4* gp2 = (const float4*)(em_table + ge2 * 32 + s * 8);
        const float4 g0 = gp1[0], g1 = gp1[1], g2 = gp2[0], g3 = gp2[1];

        // epi0: lane's values for k-chunk ktl are contiguous 8 bf16 =
        // L1 B-frag. Keep in regs + one b128 to H0 for the h2-partner.
        uint4 own[2][2];   // [pb][ktl]
        #pragma unroll
        for (int pb = 0; pb < 2; ++pb)
            #pragma unroll
            for (int ktl = 0; ktl < 2; ++ktl) {
                const f32x4 v0 = acc[pb][2 * ktl + 0];
                const f32x4 v1 = acc[pb][2 * ktl + 1];
                uint4 wv;
                wv.x = pk2(clamp01(v0[0]), clamp01(v0[1]));
                wv.y = pk2(clamp01(v0[2]), clamp01(v0[3]));
                wv.z = pk2(clamp01(v1[0]), clamp01(v1[1]));
                wv.w = pk2(clamp01(v1[2]), clamp01(v1[3]));
                own[pb][ktl] = wv;
                *(uint4*)&H0[(pbase + pb * 16 + cl) * H0S
                             + h2 * 64 + ktl * 32 + q * 8] = wv;
            }

        // ---- consume gathers: stage tile t+1 into A0n ----
        {
            const float r = feB - (float)ge1;
            uint4 d;
            d.x = pk2(g0.x + (g2.x - g0.x) * r, g0.y + (g2.y - g0.y) * r);
            d.y = pk2(g0.z + (g2.z - g0.z) * r, g0.w + (g2.w - g0.w) * r);
            d.z = pk2(g1.x + (g3.x - g1.x) * r, g1.y + (g3.y - g1.y) * r);
            d.w = pk2(g1.z + (g3.z - g1.z) * r, g1.w + (g3.w - g1.w) * r);
            *(uint4*)&A0n[p * A0S + s * 8] = d;
            if (s == 0) *(unsigned*)&A0n[p * A0S + 32] = pk2(xvB.x, xvB.y);
        }
        // prefetch fe/x for tile t+2 (3 regs live across L1 only)
        {
            int t2 = t + 2 * (int)gridDim.x; if (t2 >= TILES) t2 = t;
            const int gp = t2 * M_IT + p;
            feB = emb[gp];
            if (s == 0) xvB = *(const float2*)(x + 2 * gp);
        }
        __syncthreads();   // B2: H0 + A0n visible

        // ---- layer 1: kk=0,1 consume own[] (then dead); kk=2,3 from LDS --
        #pragma unroll
        for (int pb = 0; pb < 2; ++pb)
            #pragma unroll
            for (int hb = 0; hb < 4; ++hb)
                acc[pb][hb] = b1q[hb];
        #pragma unroll
        for (int kk = 0; kk < 2; ++kk) {
            #pragma unroll
            for (int pb = 0; pb < 2; ++pb) {
                bf16x8 bfrag;
                __builtin_memcpy(&bfrag, &own[pb][kk], 16);
                #pragma unroll
                for (int hb = 0; hb < 4; ++hb)
                    acc[pb][hb] = __builtin_amdgcn_mfma_f32_16x16x32_bf16(
                        w1r[hb][kk], bfrag, acc[pb][hb], 0, 0, 0);
            }
        }
        #pragma unroll
        for (int kk = 2; kk < 4; ++kk) {
            const int koff = (((h2 * 2 + kk) & 3) << 5) + q * 8;
            #pragma unroll
            for (int pb = 0; pb < 2; ++pb) {
                bf16x8 bfrag = *(const bf16x8*)
                    &H0[(pbase + pb * 16 + cl) * H0S + koff];
                #pragma unroll
                for (int hb = 0; hb < 4; ++hb)
                    acc[pb][hb] = __builtin_amdgcn_mfma_f32_16x16x32_bf16(
                        w1r[hb][kk], bfrag, acc[pb][hb], 0, 0, 0);
            }
        }

        // ---- epi1 + layer 2: within-lane dot over lane's 16 h2 ----
        #pragma unroll
        for (int pb = 0; pb < 2; ++pb) {
            float sum = 0.f;
            #pragma unroll
            for (int hb = 0; hb < 4; ++hb) {
                const f32x4 v = acc[pb][hb];
                sum += clamp01(v[0]) * w2q[hb][0];
                sum += clamp01(v[1]) * w2q[hb][1];
                sum += clamp01(v[2]) * w2q[hb][2];
                sum += clamp01(v[3]) * w2q[hb][3];
            }
            PART2[h2 * 4 + q][pbase + pb * 16 + cl] = sum;
        }
        __syncthreads();   // B3: PART2 visible

        if (tid < 64) {
            float z = bias2;
            #pragma unroll
            for (int i = 0; i < 8; ++i) z += PART2[i][tid];
            out[base + tid] = 1.f / (1.f + __expf(-z));
        }
        // hazards (2 barriers): H0 write(epi0,t) -> read(L1,t): B2.
        // H0 read(L1,t) -> write(epi0,t+1): B3. A0n write(t) -> L0 read
        // (t+1): B2+B3. A0c read(L0,t) -> rewrite(staging,t+1): B2+B3.
        // PART2 write(t) -> read(out,t): B3. read(t) -> write(t+1): B2(t+1).
    }
}

extern "C" void kernel_launch(void* const* d_in, const int* in_sizes, int n_in,
                              void* d_out, int out_size, void* d_ws, size_t ws_size,
                              hipStream_t stream) {
    const float* x   = (const float*)d_in[0];
    const float* emb = (const float*)d_in[1];
    const float* emt = (const float*)d_in[2];
    const float* W0  = (const float*)d_in[3];
    const float* b0  = (const float*)d_in[4];
    const float* W1  = (const float*)d_in[5];
    const float* b1  = (const float*)d_in[6];
    const float* W2  = (const float*)d_in[7];
    const float* b2  = (const float*)d_in[8];
    mlp_fused<<<NBLOCKS, 256, 0, stream>>>(x, emb, emt, W0, b0, W1, b1, W2, b2,
                                           (float*)d_out);
}